// Round 3
// baseline (1019.420 us; speedup 1.0000x reference)
//
#include <hip/hip_runtime.h>

// Model dims
#define T_ 64
#define B_ 1024
#define V_ 128
#define H_ 512

typedef short bf16x8 __attribute__((ext_vector_type(8)));
typedef float f32x4 __attribute__((ext_vector_type(4)));
typedef int int4v __attribute__((ext_vector_type(4)));

__device__ __forceinline__ unsigned short f2bf(float f) {
    union { float f; unsigned int i; } v; v.f = f;
    unsigned int x = v.i;
    return (unsigned short)((x + 0x7FFFu + ((x >> 16) & 1u)) >> 16);
}
__device__ __forceinline__ float bf2f(unsigned short u) {
    union { unsigned int i; float f; } v; v.i = ((unsigned int)u) << 16; return v.f;
}
__device__ __forceinline__ float sigm(float x) { return 1.f / (1.f + __expf(-x)); }
__device__ __forceinline__ float tanh_fast(float x) {
    float ax = fabsf(x);
    float t = 1.f - 2.f / (__expf(2.f * ax) + 1.f);   // saturates to 1 on overflow
    return copysignf(t, x);
}

// ---------------- cbias = xh_b + hh_b; zero barrier flags ----------------
__global__ __launch_bounds__(256) void cbias_k(const float* __restrict__ xh_b,
                                               const float* __restrict__ hh_b,
                                               float* __restrict__ cbias,
                                               unsigned int* __restrict__ ctr) {
    int i = blockIdx.x * 256 + threadIdx.x;          // 2048
    cbias[i] = xh_b[i] + hh_b[i];
    if (i < 512) ctr[i] = 0u;                        // flags[8][64]
}

// ---------------- convert inp fp32 -> bf16 ----------------
__global__ __launch_bounds__(256) void convx_k(const float* __restrict__ x,
                                               unsigned short* __restrict__ xbf) {
    int i = blockIdx.x * 256 + threadIdx.x;          // T*B*V = 8388608
    xbf[i] = f2bf(x[i]);
}

// ---------------- build Wt bf16 [2048][640]: Wt[n][k] = W[k][n] ----------------
__global__ __launch_bounds__(256) void convw_k(const float* __restrict__ xw,
                                               const float* __restrict__ hw,
                                               unsigned short* __restrict__ wt) {
    int i = blockIdx.x * 256 + threadIdx.x;          // 2048*640 = 1310720
    int n = i / 640, k = i - n * 640;
    float v = (k < 128) ? xw[k * 2048 + n] : hw[(k - 128) * 2048 + n];
    wt[i] = f2bf(v);
}

// ---------------- build Wo bf16 [128][512]: Wo[n][k] = out_w[k][n] ----------------
__global__ __launch_bounds__(256) void convow_k(const float* __restrict__ ow,
                                                unsigned short* __restrict__ wo) {
    int i = blockIdx.x * 256 + threadIdx.x;          // 128*512 = 65536
    int n = i >> 9, k = i & 511;
    wo[i] = f2bf(ow[k * 128 + n]);
}

// ---------------- conv1 3x3 pad1 + relu + 2x2 maxpool ----------------
__global__ __launch_bounds__(256) void conv1_k(const float* __restrict__ img,
                                               const float* __restrict__ w,
                                               const float* __restrict__ bias,
                                               float* __restrict__ out) {
    int id = blockIdx.x * 256 + threadIdx.x;         // B*8*32*32 = 8388608
    int px = id & 31, py = (id >> 5) & 31, oc = (id >> 10) & 7, b = id >> 13;
    const float* ip = img + b * 4096;
    float wv[9];
#pragma unroll
    for (int t = 0; t < 9; ++t) wv[t] = w[oc * 9 + t];
    float bs = bias[oc];
    float m = -3.4e38f;
#pragma unroll
    for (int sy = 0; sy < 2; ++sy)
#pragma unroll
    for (int sx = 0; sx < 2; ++sx) {
        int oy = 2 * py + sy, ox = 2 * px + sx;
        float acc = bs;
#pragma unroll
        for (int ky = 0; ky < 3; ++ky) {
            int iy = oy + ky - 1;
            if (iy < 0 || iy > 63) continue;
#pragma unroll
            for (int kx = 0; kx < 3; ++kx) {
                int ix = ox + kx - 1;
                if (ix < 0 || ix > 63) continue;
                acc += ip[iy * 64 + ix] * wv[ky * 3 + kx];
            }
        }
        m = fmaxf(m, acc);
    }
    out[id] = fmaxf(m, 0.f);
}

// ---------------- conv2 5x5 pad1 + relu + 2x2 maxpool ----------------
__device__ __forceinline__ int c2idx(int ic, int y, int x) {
    return ((ic * 34 + y) * 2 + (x & 1)) * 18 + (x >> 1);
}
__global__ __launch_bounds__(256) void conv2_k(const float* __restrict__ in,
                                               const float* __restrict__ w,
                                               const float* __restrict__ bias,
                                               float* __restrict__ feat) {
    __shared__ float in_s[8 * 34 * 36];
    __shared__ float w_s[3200];
    __shared__ float b_s[16];
    int tid = threadIdx.x, b = blockIdx.x;
    for (int e = tid; e < 8 * 34 * 34; e += 256) {
        int ic = e / 1156, r = e - ic * 1156;
        int y = r / 34, xx = r - y * 34;
        float v = 0.f;
        if (y >= 1 && y <= 32 && xx >= 1 && xx <= 32)
            v = in[b * 8192 + ic * 1024 + (y - 1) * 32 + (xx - 1)];
        in_s[c2idx(ic, y, xx)] = v;
    }
    for (int e = tid; e < 3200; e += 256) w_s[e] = w[e];
    if (tid < 16) b_s[tid] = bias[tid];
    __syncthreads();
    for (int o = tid; o < 3600; o += 256) {
        int oc = o / 225, p = o - oc * 225;
        int py = p / 15, px = p - py * 15;
        float a00, a01, a10, a11;
        a00 = a01 = a10 = a11 = b_s[oc];
        for (int ic = 0; ic < 8; ++ic) {
            const float* wp = w_s + (oc * 8 + ic) * 25;
#pragma unroll
            for (int ky = 0; ky < 5; ++ky) {
                int y0 = 2 * py + ky;
                float r0[6], r1[6];
#pragma unroll
                for (int xx = 0; xx < 6; ++xx) {
                    r0[xx] = in_s[c2idx(ic, y0,     2 * px + xx)];
                    r1[xx] = in_s[c2idx(ic, y0 + 1, 2 * px + xx)];
                }
#pragma unroll
                for (int kx = 0; kx < 5; ++kx) {
                    float wv = wp[ky * 5 + kx];
                    a00 += r0[kx    ] * wv;
                    a01 += r0[kx + 1] * wv;
                    a10 += r1[kx    ] * wv;
                    a11 += r1[kx + 1] * wv;
                }
            }
        }
        float mx = fmaxf(fmaxf(a00, a01), fmaxf(a10, a11));
        feat[b * 3600 + o] = fmaxf(mx, 0.f);
    }
}

// ---------------- imgfc: e = relu(feat @ W + b), M=1024 N=512 K=3600 ----------------
__global__ __launch_bounds__(256) void imgfc_gemm(const float* __restrict__ A,
                                                  const float* __restrict__ W,
                                                  const float* __restrict__ bias,
                                                  float* __restrict__ E) {
    __shared__ __align__(16) float As[16][68];
    __shared__ __align__(16) float Bs[16][68];
    const int tid = threadIdx.x;
    const int tx = tid & 15, ty = tid >> 4;
    const int row0 = blockIdx.y * 64, col0 = blockIdx.x * 64;
    const int am = tid >> 2, ak = (tid & 3) * 4;
    const int bk = tid >> 4, bn = (tid & 15) * 4;
    float acc[4][4] = {};
    for (int k0 = 0; k0 < 3600; k0 += 16) {
        float4 fa = *(const float4*)(A + (row0 + am) * 3600 + k0 + ak);
        float4 fb = *(const float4*)(W + (k0 + bk) * 512 + col0 + bn);
        __syncthreads();
        As[ak + 0][am] = fa.x; As[ak + 1][am] = fa.y; As[ak + 2][am] = fa.z; As[ak + 3][am] = fa.w;
        Bs[bk][bn + 0] = fb.x; Bs[bk][bn + 1] = fb.y; Bs[bk][bn + 2] = fb.z; Bs[bk][bn + 3] = fb.w;
        __syncthreads();
#pragma unroll
        for (int kk = 0; kk < 16; ++kk) {
            float4 av = *(const float4*)(&As[kk][ty * 4]);
            float4 bv = *(const float4*)(&Bs[kk][tx * 4]);
            float a[4] = {av.x, av.y, av.z, av.w};
            float bb[4] = {bv.x, bv.y, bv.z, bv.w};
#pragma unroll
            for (int i = 0; i < 4; ++i)
#pragma unroll
            for (int j = 0; j < 4; ++j) acc[i][j] += a[i] * bb[j];
        }
    }
#pragma unroll
    for (int i = 0; i < 4; ++i) {
        int r = row0 + ty * 4 + i;
#pragma unroll
        for (int j = 0; j < 4; ++j) {
            int cI = col0 + tx * 4 + j;
            E[r * 512 + cI] = fmaxf(acc[i][j] + bias[cI], 0.f);
        }
    }
}

#define MFMA16(a, b, c) __builtin_amdgcn_mfma_f32_16x16x32_bf16((a), (b), (c), 0, 0, 0)

// ---------------- persistent LSTM: all 64 steps in one dispatch ----------------
// 256 blocks x 512 threads (8 waves). Block = (rg, jblk), rg = blockIdx&7 (XCD
// swizzle: barrier group lives on one XCD). Wave = 16 rows x 16 cols x ALL 4
// gates; block's B-slice (64 wt-rows x 640 k = 81 KB) lives in LDS (padded,
// conflict-light ds_read_b128).
//
// hs is PANEL-MAJOR: hs[t][panel=j/16][1024 rows][16 cols] bf16. A wave's
// 16x16 output tile is one contiguous 512 B block -> one coalesced
// global_store_dwordx4 sc0 sc1 per wave per step (via 512 B LDS repack);
// h loads read two contiguous 512 B blocks per instruction (100% line use).
//
// h-tile is REGISTER-PREFETCHED: all 16 bf16x8 loads issue back-to-back
// (static-index areg[16], ~64 VGPR) so one load latency is exposed per step
// instead of 16 (R2 showed VGPR=44 -> compiler had no pipelining headroom).
//
// Cross-block sync: per-block arrival FLAGS (no atomic RMW). All waves drain
// vmcnt EXPLICITLY (inline-asm store is invisible to the compiler's
// waitcnt-before-barrier logic), barrier A, then tid0 writes flags[jblk]=t
// (relaxed, agent); wave 0's lanes poll all 32 flags in parallel (one 128 B
// line) with __all(v>=t). Monotonic >= makes block skew safe. No s_sleep:
// the ~600cyc agent-scope poll round trip is natural pacing.
__global__ __launch_bounds__(512, 2) void lstm_persist(
        const unsigned short* __restrict__ xbf,   // [T,B,128] bf16
        const unsigned short* __restrict__ wt,    // [2048,640] bf16
        const float* __restrict__ cbias,          // [2048]
        const float* __restrict__ eimg,           // [B,512]
        unsigned short* __restrict__ hs,          // [T,32,1024,16] bf16 panel-major
        unsigned int* __restrict__ ctr) {         // flags [8][64]
    extern __shared__ unsigned short w_s[];       // [64][648] weights + [8][256] repack
    unsigned short* scr = w_s + 64 * 648;
    const int tid = threadIdx.x;
    const int wave = tid >> 6, lane = tid & 63;
    const int quad = lane >> 4, l16 = lane & 15;
    const int rg = blockIdx.x & 7;                // XCD swizzle
    const int jblk = blockIdx.x >> 3;
    const int j0 = jblk * 16;
    const int rowbase = rg * 128 + wave * 16;
    unsigned int* flags = ctr + rg * 64;

    // stage the block's weight slice: 64 rows (4 gates x 16 j) x 640 k
    for (int e = tid; e < 64 * 80; e += 512) {
        int r = e / 80, c8 = (e - r * 80) * 8;
        int g = r >> 4, rr = r & 15;
        *(bf16x8*)(w_s + r * 648 + c8) =
            *(const bf16x8*)(wt + (size_t)(g * 512 + j0 + rr) * 640 + c8);
    }
    const int j = j0 + l16;
    const float cb0 = cbias[j], cb1 = cbias[512 + j], cb2 = cbias[1024 + j], cb3 = cbias[1536 + j];
    __syncthreads();

    float cst[4];
    f32x4 acc[4];
#pragma unroll
    for (int g = 0; g < 4; ++g) acc[g] = (f32x4){0.f, 0.f, 0.f, 0.f};

    // x-part for t=0 (prefetch loads, then MFMA)
    {
        bf16x8 xreg[4];
#pragma unroll
        for (int kk = 0; kk < 4; ++kk)
            xreg[kk] = *(const bf16x8*)(xbf + (size_t)(rowbase + l16) * 128 + kk * 32 + quad * 8);
#pragma unroll
        for (int kk = 0; kk < 4; ++kk)
#pragma unroll
            for (int g = 0; g < 4; ++g) {
                bf16x8 b = *(const bf16x8*)(w_s + (size_t)(g * 16 + l16) * 648 + kk * 32 + quad * 8);
                acc[g] = MFMA16(xreg[kk], b, acc[g]);
            }
    }

#pragma unroll 1
    for (int t = 0; t < T_; ++t) {
        if (t > 0) {
            // ALL waves: guarantee the prior-step sc1 store is at MALL before
            // the barrier (compiler can't see the inline-asm store's vmcnt).
            asm volatile("s_waitcnt vmcnt(0)" ::: "memory");
            __syncthreads();                      // A: all waves' stores drained
            if (tid == 0)
                __hip_atomic_store(flags + jblk, (unsigned int)t,
                                   __ATOMIC_RELAXED, __HIP_MEMORY_SCOPE_AGENT);
            if (wave == 0) {
                int guard = 0;
                for (;;) {
                    unsigned int v = __hip_atomic_load(flags + (lane & 31),
                                                       __ATOMIC_RELAXED, __HIP_MEMORY_SCOPE_AGENT);
                    if (__all((int)(v >= (unsigned int)t)) || ++guard > (1 << 20)) break;
                }
            }
            __syncthreads();                      // B: release
            // panel-major h loads: per kk, quads 0/1 read panel 2kk, quads 2/3
            // panel 2kk+1 -> two contiguous 512 B blocks per instruction.
            // Prefetch ALL 16 into registers (one exposed latency), then MFMA.
            const unsigned short* ha = hs + (size_t)(t - 1) * (B_ * H_)
                                          + (size_t)(rowbase + l16) * 16 + (quad & 1) * 8;
            bf16x8 areg[16];
#pragma unroll
            for (int kk = 0; kk < 16; ++kk)
                areg[kk] = *(const bf16x8*)(ha + (size_t)(kk * 2 + (quad >> 1)) * 16384);
#pragma unroll
            for (int kk = 0; kk < 16; ++kk)
#pragma unroll
                for (int g = 0; g < 4; ++g) {
                    bf16x8 b = *(const bf16x8*)(w_s + (size_t)(g * 16 + l16) * 648 + 128 + kk * 32 + quad * 8);
                    acc[g] = MFMA16(areg[kk], b, acc[g]);
                }
        }
        // epilogue: C/D layout col=l16, row=quad*4+reg; repack wave tile in LDS,
        // then one coalesced 512 B sc1 store (32 lanes x 16 B).
        unsigned short* scw = scr + wave * 256;
#pragma unroll
        for (int reg = 0; reg < 4; ++reg) {
            int row = rowbase + quad * 4 + reg;
            float ea = (t == 0) ? eimg[(size_t)row * 512 + j] : 0.f;
            float iv = sigm(acc[0][reg] + cb0 + ea);
            float fv = sigm(acc[1][reg] + cb1 + ea);
            float gv = tanh_fast(acc[2][reg] + cb2 + ea);
            float ov = sigm(acc[3][reg] + cb3 + ea);
            float co = (t == 0) ? 0.f : cst[reg];
            float cn = fv * co + iv * gv;
            cst[reg] = cn;
            scw[(quad * 4 + reg) * 16 + l16] = f2bf(ov * tanh_fast(cn));
        }
        if (lane < 32) {
            int4v v = *(const int4v*)(scw + lane * 8);   // compiler inserts lgkm wait
            unsigned short* gp = hs + (size_t)t * (B_ * H_)
                                    + (size_t)jblk * 16384 + (size_t)rowbase * 16 + lane * 8;
            asm volatile("global_store_dwordx4 %0, %1, off sc0 sc1" :: "v"(gp), "v"(v) : "memory");
        }
        if (t < T_ - 1) {
            // pre-compute x-part(t+1) while the store drains / flags propagate
#pragma unroll
            for (int g = 0; g < 4; ++g) acc[g] = (f32x4){0.f, 0.f, 0.f, 0.f};
            const unsigned short* xtp = xbf + (size_t)(t + 1) * (B_ * V_);
            bf16x8 xreg[4];
#pragma unroll
            for (int kk = 0; kk < 4; ++kk)
                xreg[kk] = *(const bf16x8*)(xtp + (size_t)(rowbase + l16) * 128 + kk * 32 + quad * 8);
#pragma unroll
            for (int kk = 0; kk < 4; ++kk)
#pragma unroll
                for (int g = 0; g < 4; ++g) {
                    bf16x8 b = *(const bf16x8*)(w_s + (size_t)(g * 16 + l16) * 648 + kk * 32 + quad * 8);
                    acc[g] = MFMA16(xreg[kk], b, acc[g]);
                }
        }
    }
}

// ---------------- logits + log_softmax via MFMA ----------------
__global__ __launch_bounds__(256, 2) void logits_mfma(
        const unsigned short* __restrict__ hs,    // [T,32,1024,16] bf16 panel-major
        const unsigned short* __restrict__ wo,    // [128][512] bf16, k-major
        const float* __restrict__ ob,             // [128]
        float* __restrict__ out) {                // [65536,128]
    __shared__ unsigned short wos[128 * 264];
    const int tid = threadIdx.x;
    const int wave = tid >> 6, lane = tid & 63;
    const int quad = lane >> 4, l16 = lane & 15;
    const int row0 = blockIdx.x * 64 + wave * 16;
    const int trow = row0 >> 10;                  // all 16 rows of this wave share t
    const int b0 = row0 & 1023;
    const unsigned short* hbase = hs + (size_t)trow * (B_ * H_)
                                     + (size_t)(b0 + l16) * 16 + (quad & 1) * 8;
    f32x4 acc[8];
#pragma unroll
    for (int q = 0; q < 8; ++q) acc[q] = (f32x4){0.f, 0.f, 0.f, 0.f};

    for (int half = 0; half < 2; ++half) {
        __syncthreads();
        for (int e = tid; e < 128 * 32; e += 256) {
            int n = e >> 5, c8 = (e & 31) * 8;
            *(bf16x8*)(wos + n * 264 + c8) = *(const bf16x8*)(wo + n * 512 + half * 256 + c8);
        }
        __syncthreads();
#pragma unroll
        for (int ki = 0; ki < 8; ++ki) {
            int p = half * 16 + ki * 2 + (quad >> 1);
            bf16x8 a = *(const bf16x8*)(hbase + (size_t)p * 16384);
#pragma unroll
            for (int tn = 0; tn < 8; ++tn) {
                bf16x8 b = *(const bf16x8*)(wos + (tn * 16 + l16) * 264 + ki * 32 + quad * 8);
                acc[tn] = MFMA16(a, b, acc[tn]);
            }
        }
    }
    float bia[8];
#pragma unroll
    for (int tn = 0; tn < 8; ++tn) bia[tn] = ob[tn * 16 + l16];
#pragma unroll
    for (int reg = 0; reg < 4; ++reg) {
        float v[8];
        float m = -3.4e38f;
#pragma unroll
        for (int tn = 0; tn < 8; ++tn) { v[tn] = acc[tn][reg] + bia[tn]; m = fmaxf(m, v[tn]); }
#pragma unroll
        for (int off = 1; off < 16; off <<= 1) m = fmaxf(m, __shfl_xor(m, off, 64));
        float s = 0.f;
#pragma unroll
        for (int tn = 0; tn < 8; ++tn) s += __expf(v[tn] - m);
#pragma unroll
        for (int off = 1; off < 16; off <<= 1) s += __shfl_xor(s, off, 64);
        float z = m + __logf(s);
        int row = row0 + quad * 4 + reg;
        float* op = out + (size_t)row * 128;
#pragma unroll
        for (int tn = 0; tn < 8; ++tn) op[tn * 16 + l16] = v[tn] - z;
    }
}

extern "C" void kernel_launch(void* const* d_in, const int* in_sizes, int n_in,
                              void* d_out, int out_size, void* d_ws, size_t ws_size,
                              hipStream_t stream) {
    const float* inp     = (const float*)d_in[0];
    const float* img     = (const float*)d_in[1];
    const float* conv1_w = (const float*)d_in[2];
    const float* conv1_b = (const float*)d_in[3];
    const float* conv2_w = (const float*)d_in[4];
    const float* conv2_b = (const float*)d_in[5];
    const float* imgfc_w = (const float*)d_in[6];
    const float* imgfc_b = (const float*)d_in[7];
    const float* xh_w    = (const float*)d_in[8];
    const float* xh_b    = (const float*)d_in[9];
    const float* hh_w    = (const float*)d_in[10];
    const float* hh_b    = (const float*)d_in[11];
    const float* out_w   = (const float*)d_in[12];
    const float* out_b   = (const float*)d_in[13];

    // ws layout (~90 MB). conv1out/feat alias the hs region (dead before
    // lstm_persist writes hs[0]).
    char* ws = (char*)d_ws;
    unsigned short* hs  = (unsigned short*)(ws);                   // [0,64M): panel-major bf16
    float* conv1out     = (float*)(ws);                            // [0,32M) alias
    float* feat         = (float*)(ws + (32u << 20));              // [32,46.2M) alias
    float* e            = (float*)(ws + (64u << 20));              // 2 MB
    float* cbias        = (float*)(ws + (66u << 20));              // 8 KB
    unsigned short* xbf = (unsigned short*)(ws + (67u << 20));     // 16 MB
    unsigned short* wt  = (unsigned short*)(ws + (83u << 20));     // 2.56 MB
    unsigned short* wo  = (unsigned short*)(ws + (86u << 20));     // 128 KB
    unsigned int*  ctr  = (unsigned int*)(ws + (87u << 20));       // flags [8][64]
    float* outp         = (float*)d_out;

    cbias_k<<<8, 256, 0, stream>>>(xh_b, hh_b, cbias, ctr);
    convx_k<<<(T_ * B_ * V_) / 256, 256, 0, stream>>>(inp, xbf);
    convw_k<<<(2048 * 640) / 256, 256, 0, stream>>>(xh_w, hh_w, wt);
    convow_k<<<(128 * 512) / 256, 256, 0, stream>>>(out_w, wo);
    conv1_k<<<(B_ * 8 * 32 * 32) / 256, 256, 0, stream>>>(img, conv1_w, conv1_b, conv1out);
    conv2_k<<<B_, 256, 0, stream>>>(conv1out, conv2_w, conv2_b, feat);
    imgfc_gemm<<<dim3(8, 16), 256, 0, stream>>>(feat, imgfc_w, imgfc_b, e);

    lstm_persist<<<256, 512, (64 * 648 + 8 * 256) * sizeof(unsigned short), stream>>>(
        xbf, wt, cbias, e, hs, ctr);

    logits_mfma<<<(T_ * B_) / 64, 256, 0, stream>>>(hs, wo, out_b, outp);
}

// Round 4
// 964.288 us; speedup vs baseline: 1.0572x; 1.0572x over previous
//
#include <hip/hip_runtime.h>

// Model dims
#define T_ 64
#define B_ 1024
#define V_ 128
#define H_ 512

typedef short bf16x8 __attribute__((ext_vector_type(8)));
typedef short bf16x4 __attribute__((ext_vector_type(4)));
typedef float f32x4 __attribute__((ext_vector_type(4)));
typedef float f32x16 __attribute__((ext_vector_type(16)));
typedef int int4v __attribute__((ext_vector_type(4)));

#define ZERO16 ((f32x16){0.f,0.f,0.f,0.f,0.f,0.f,0.f,0.f,0.f,0.f,0.f,0.f,0.f,0.f,0.f,0.f})

__device__ __forceinline__ unsigned short f2bf(float f) {
    union { float f; unsigned int i; } v; v.f = f;
    unsigned int x = v.i;
    return (unsigned short)((x + 0x7FFFu + ((x >> 16) & 1u)) >> 16);
}
__device__ __forceinline__ float sigm(float x) { return 1.f / (1.f + __expf(-x)); }
__device__ __forceinline__ float tanh_fast(float x) {
    float ax = fabsf(x);
    float t = 1.f - 2.f / (__expf(2.f * ax) + 1.f);   // saturates to 1 on overflow
    return copysignf(t, x);
}

// ---------------- cbias = xh_b + hh_b; zero barrier flags ----------------
__global__ __launch_bounds__(256) void cbias_k(const float* __restrict__ xh_b,
                                               const float* __restrict__ hh_b,
                                               float* __restrict__ cbias,
                                               unsigned int* __restrict__ ctr) {
    int i = blockIdx.x * 256 + threadIdx.x;          // 2048
    cbias[i] = xh_b[i] + hh_b[i];
    if (i < 512) ctr[i] = 0u;                        // flags[8][64]
}

// ---------------- convert inp fp32 -> bf16, PANEL-MAJOR [T][8][1024][16] ----------------
__global__ __launch_bounds__(256) void convx_k(const float* __restrict__ x,
                                               unsigned short* __restrict__ xbf) {
    int e = blockIdx.x * 256 + threadIdx.x;          // T*B*8 = 524288
    int t = e >> 13, r = e & 8191;
    int panel = r >> 10, b = r & 1023;
    const float* ip = x + ((size_t)t * 1024 + b) * 128 + panel * 16;
    unsigned short* op = xbf + (size_t)t * 131072 + panel * 16384 + b * 16;
#pragma unroll
    for (int h = 0; h < 2; ++h) {
        float4 f0 = *(const float4*)(ip + h * 8);
        float4 f1 = *(const float4*)(ip + h * 8 + 4);
        bf16x8 o;
        o[0] = (short)f2bf(f0.x); o[1] = (short)f2bf(f0.y);
        o[2] = (short)f2bf(f0.z); o[3] = (short)f2bf(f0.w);
        o[4] = (short)f2bf(f1.x); o[5] = (short)f2bf(f1.y);
        o[6] = (short)f2bf(f1.z); o[7] = (short)f2bf(f1.w);
        *(bf16x8*)(op + h * 8) = o;
    }
}

// ---------------- build Wt bf16 [2048][640]: Wt[n][k] = W[k][n] ----------------
__global__ __launch_bounds__(256) void convw_k(const float* __restrict__ xw,
                                               const float* __restrict__ hw,
                                               unsigned short* __restrict__ wt) {
    int i = blockIdx.x * 256 + threadIdx.x;          // 2048*640 = 1310720
    int n = i / 640, k = i - n * 640;
    float v = (k < 128) ? xw[k * 2048 + n] : hw[(k - 128) * 2048 + n];
    wt[i] = f2bf(v);
}

// ---------------- build Wo bf16 [128][512]: Wo[n][k] = out_w[k][n] ----------------
__global__ __launch_bounds__(256) void convow_k(const float* __restrict__ ow,
                                                unsigned short* __restrict__ wo) {
    int i = blockIdx.x * 256 + threadIdx.x;          // 128*512 = 65536
    int n = i >> 9, k = i & 511;
    wo[i] = f2bf(ow[k * 128 + n]);
}

// ---------------- conv1 3x3 pad1 + relu + 2x2 maxpool ----------------
__global__ __launch_bounds__(256) void conv1_k(const float* __restrict__ img,
                                               const float* __restrict__ w,
                                               const float* __restrict__ bias,
                                               float* __restrict__ out) {
    int id = blockIdx.x * 256 + threadIdx.x;         // B*8*32*32 = 8388608
    int px = id & 31, py = (id >> 5) & 31, oc = (id >> 10) & 7, b = id >> 13;
    const float* ip = img + b * 4096;
    float wv[9];
#pragma unroll
    for (int t = 0; t < 9; ++t) wv[t] = w[oc * 9 + t];
    float bs = bias[oc];
    float m = -3.4e38f;
#pragma unroll
    for (int sy = 0; sy < 2; ++sy)
#pragma unroll
    for (int sx = 0; sx < 2; ++sx) {
        int oy = 2 * py + sy, ox = 2 * px + sx;
        float acc = bs;
#pragma unroll
        for (int ky = 0; ky < 3; ++ky) {
            int iy = oy + ky - 1;
            if (iy < 0 || iy > 63) continue;
#pragma unroll
            for (int kx = 0; kx < 3; ++kx) {
                int ix = ox + kx - 1;
                if (ix < 0 || ix > 63) continue;
                acc += ip[iy * 64 + ix] * wv[ky * 3 + kx];
            }
        }
        m = fmaxf(m, acc);
    }
    out[id] = fmaxf(m, 0.f);
}

// ---------------- conv2 5x5 pad1 + relu + 2x2 maxpool ----------------
__device__ __forceinline__ int c2idx(int ic, int y, int x) {
    return ((ic * 34 + y) * 2 + (x & 1)) * 18 + (x >> 1);
}
__global__ __launch_bounds__(256) void conv2_k(const float* __restrict__ in,
                                               const float* __restrict__ w,
                                               const float* __restrict__ bias,
                                               float* __restrict__ feat) {
    __shared__ float in_s[8 * 34 * 36];
    __shared__ float w_s[3200];
    __shared__ float b_s[16];
    int tid = threadIdx.x, b = blockIdx.x;
    for (int e = tid; e < 8 * 34 * 34; e += 256) {
        int ic = e / 1156, r = e - ic * 1156;
        int y = r / 34, xx = r - y * 34;
        float v = 0.f;
        if (y >= 1 && y <= 32 && xx >= 1 && xx <= 32)
            v = in[b * 8192 + ic * 1024 + (y - 1) * 32 + (xx - 1)];
        in_s[c2idx(ic, y, xx)] = v;
    }
    for (int e = tid; e < 3200; e += 256) w_s[e] = w[e];
    if (tid < 16) b_s[tid] = bias[tid];
    __syncthreads();
    for (int o = tid; o < 3600; o += 256) {
        int oc = o / 225, p = o - oc * 225;
        int py = p / 15, px = p - py * 15;
        float a00, a01, a10, a11;
        a00 = a01 = a10 = a11 = b_s[oc];
        for (int ic = 0; ic < 8; ++ic) {
            const float* wp = w_s + (oc * 8 + ic) * 25;
#pragma unroll
            for (int ky = 0; ky < 5; ++ky) {
                int y0 = 2 * py + ky;
                float r0[6], r1[6];
#pragma unroll
                for (int xx = 0; xx < 6; ++xx) {
                    r0[xx] = in_s[c2idx(ic, y0,     2 * px + xx)];
                    r1[xx] = in_s[c2idx(ic, y0 + 1, 2 * px + xx)];
                }
#pragma unroll
                for (int kx = 0; kx < 5; ++kx) {
                    float wv = wp[ky * 5 + kx];
                    a00 += r0[kx    ] * wv;
                    a01 += r0[kx + 1] * wv;
                    a10 += r1[kx    ] * wv;
                    a11 += r1[kx + 1] * wv;
                }
            }
        }
        float mx = fmaxf(fmaxf(a00, a01), fmaxf(a10, a11));
        feat[b * 3600 + o] = fmaxf(mx, 0.f);
    }
}

// ---------------- imgfc: e = relu(feat @ W + b), M=1024 N=512 K=3600 ----------------
// 64x32 tiles -> 256 blocks (full GPU; the old 64x64 grid was 128 blocks).
__global__ __launch_bounds__(256) void imgfc_gemm(const float* __restrict__ A,
                                                  const float* __restrict__ W,
                                                  const float* __restrict__ bias,
                                                  float* __restrict__ E) {
    __shared__ __align__(16) float As[16][68];
    __shared__ __align__(16) float Bs[16][36];
    const int tid = threadIdx.x;
    const int tx = tid & 15, ty = tid >> 4;
    const int row0 = blockIdx.y * 64, col0 = blockIdx.x * 32;
    const int am = tid >> 2, ak = (tid & 3) * 4;
    const int bk = tid >> 4, bn = (tid & 15) * 2;
    float acc[4][2] = {};
    for (int k0 = 0; k0 < 3600; k0 += 16) {
        float4 fa = *(const float4*)(A + (row0 + am) * 3600 + k0 + ak);
        float2 fb = *(const float2*)(W + (k0 + bk) * 512 + col0 + bn);
        __syncthreads();
        As[ak + 0][am] = fa.x; As[ak + 1][am] = fa.y; As[ak + 2][am] = fa.z; As[ak + 3][am] = fa.w;
        Bs[bk][bn] = fb.x; Bs[bk][bn + 1] = fb.y;
        __syncthreads();
#pragma unroll
        for (int kk = 0; kk < 16; ++kk) {
            float4 av = *(const float4*)(&As[kk][ty * 4]);
            float a[4] = {av.x, av.y, av.z, av.w};
            float b0 = Bs[kk][tx * 2], b1 = Bs[kk][tx * 2 + 1];
#pragma unroll
            for (int i = 0; i < 4; ++i) { acc[i][0] += a[i] * b0; acc[i][1] += a[i] * b1; }
        }
    }
#pragma unroll
    for (int i = 0; i < 4; ++i) {
        int rr = row0 + ty * 4 + i;
#pragma unroll
        for (int j = 0; j < 2; ++j) {
            int cI = col0 + tx * 2 + j;
            E[rr * 512 + cI] = fmaxf(acc[i][j] + bias[cI], 0.f);
        }
    }
}

#define MFMA16(a, b, c) __builtin_amdgcn_mfma_f32_16x16x32_bf16((a), (b), (c), 0, 0, 0)
#define MFMA32(a, b, c) __builtin_amdgcn_mfma_f32_32x32x16_bf16((a), (b), (c), 0, 0, 0)

// ---------------- persistent LSTM: all 64 steps in one dispatch ----------------
// 256 blocks x 512 threads (8 waves). Block = (rg, jblk): rg = blockIdx&7,
// jblk = 16 j-cols. Wave = (rt, ks): rt = batch row-tile of 32, ks = K-half.
// 32x32x16 MFMA with OPERAND SWAP: A = weights (rows = gate-cols cc = g*16+j),
// B = h/x (cols = batch). C/D: col = lane&31 = batch, rows over regs -> each
// lane holds ALL FOUR GATES of its 8 (row, j) cells: no gate exchange.
// K-split partials summed via LDS xbuf ([rt][q][lane][4] f32, conflict-free)
// + barrier C; ks=0 waves run the epilogue, keep cst, and store.
// w-fragment LDS reads per CU-step halve vs the 16x16 structure (640->320 b128).
// h-fragment global loads are register-prefetched and PINNED with
// sched_barrier(0) (R3 showed the compiler sinks unpinned prefetches).
__global__ __launch_bounds__(512, 2) void lstm_persist(
        const unsigned short* __restrict__ xbf,   // [T,8,1024,16] bf16 panel-major
        const unsigned short* __restrict__ wt,    // [2048,640] bf16
        const float* __restrict__ cbias,          // [2048]
        const float* __restrict__ eimg,           // [B,512]
        unsigned short* __restrict__ hs,          // [T,32,1024,16] bf16 panel-major
        unsigned int* __restrict__ ctr) {         // flags [8][64]
    extern __shared__ unsigned char smem[];
    unsigned short* w_s = (unsigned short*)smem;                    // [64][648] = 82944 B
    float* xbuf = (float*)(smem + 82944);                           // [4][8][64][4] = 32 KB
    unsigned short* scr = (unsigned short*)(smem + 82944 + 32768);  // [4][32][16] = 4 KB
    const int tid = threadIdx.x;
    const int wave = tid >> 6, lane = tid & 63;
    const int l31 = lane & 31, lh = lane >> 5, h8 = lh * 8;
    const int rt = wave & 3, ks = wave >> 2;
    const int rg = blockIdx.x & 7;                // XCD swizzle
    const int jblk = blockIdx.x >> 3;
    const int j0 = jblk * 16;
    const int rowbase = rg * 128 + rt * 32;
    unsigned int* flags = ctr + rg * 64;

    // stage the block's weight slice: 64 rows (cc = g*16+j) x 640 k, stride 648
    for (int e = tid; e < 64 * 80; e += 512) {
        int r = e / 80, c8 = (e - r * 80) * 8;
        int g = r >> 4, rr = r & 15;
        *(bf16x8*)(w_s + r * 648 + c8) =
            *(const bf16x8*)(wt + (size_t)(g * 512 + j0 + rr) * 640 + c8);
    }
    // per-lane bias vectors: cell j = qq*8 + lh*4 + jj
    f32x4 cbi[2], cbf_[2], cbg[2], cbo[2];
#pragma unroll
    for (int qq = 0; qq < 2; ++qq) {
        cbi[qq]  = *(const f32x4*)(cbias +        j0 + qq * 8 + lh * 4);
        cbf_[qq] = *(const f32x4*)(cbias +  512 + j0 + qq * 8 + lh * 4);
        cbg[qq]  = *(const f32x4*)(cbias + 1024 + j0 + qq * 8 + lh * 4);
        cbo[qq]  = *(const f32x4*)(cbias + 1536 + j0 + qq * 8 + lh * 4);
    }
    __syncthreads();

    float cst[8];
    f32x16 acc0 = ZERO16, acc1 = ZERO16;

    // x-part for t=0 (this wave's K-half)
    {
        const unsigned short* xp = xbf + (size_t)(ks * 4) * 16384
                                       + (size_t)(rowbase + l31) * 16 + h8;
        bf16x8 xreg[4];
#pragma unroll
        for (int kk = 0; kk < 4; ++kk) xreg[kk] = *(const bf16x8*)(xp + kk * 16384);
        __builtin_amdgcn_sched_barrier(0);
        const unsigned short* wx = w_s + (size_t)l31 * 648 + ks * 64 + h8;
#pragma unroll
        for (int kk = 0; kk < 4; ++kk) {
            bf16x8 a0 = *(const bf16x8*)(wx + kk * 16);
            bf16x8 a1 = *(const bf16x8*)(wx + 32 * 648 + kk * 16);
            acc0 = MFMA32(a0, xreg[kk], acc0);
            acc1 = MFMA32(a1, xreg[kk], acc1);
        }
    }

#pragma unroll 1
    for (int t = 0; t < T_; ++t) {
        if (t > 0) {
            // drain prior-step sc1 store (inline-asm store invisible to compiler)
            asm volatile("s_waitcnt vmcnt(0)" ::: "memory");
            __syncthreads();                      // A
            if (tid == 0)
                __hip_atomic_store(flags + jblk, (unsigned int)t,
                                   __ATOMIC_RELAXED, __HIP_MEMORY_SCOPE_AGENT);
            if (wave == 0) {
                int guard = 0;
                for (;;) {
                    unsigned int v = __hip_atomic_load(flags + l31,
                                                       __ATOMIC_RELAXED, __HIP_MEMORY_SCOPE_AGENT);
                    if (__all((int)(v >= (unsigned int)t)) || ++guard > (1 << 20)) break;
                }
            }
            __syncthreads();                      // B
            // h B-fragments: 16 contiguous 1 KB panel reads, prefetched+pinned
            const unsigned short* hp = hs + (size_t)(t - 1) * (B_ * H_)
                                          + (size_t)(ks * 16) * 16384
                                          + (size_t)(rowbase + l31) * 16 + h8;
            bf16x8 breg[16];
#pragma unroll
            for (int kk = 0; kk < 16; ++kk) breg[kk] = *(const bf16x8*)(hp + (size_t)kk * 16384);
            __builtin_amdgcn_sched_barrier(0);
            const unsigned short* wh = w_s + (size_t)l31 * 648 + 128 + ks * 256 + h8;
#pragma unroll
            for (int kk = 0; kk < 16; ++kk) {
                bf16x8 a0 = *(const bf16x8*)(wh + kk * 16);
                bf16x8 a1 = *(const bf16x8*)(wh + 32 * 648 + kk * 16);
                acc0 = MFMA32(a0, breg[kk], acc0);
                acc1 = MFMA32(a1, breg[kk], acc1);
            }
        }
        // ---- K-split exchange: ks=1 writes partials, ks=0 sums ----
        if (ks == 1) {
            float* xb = xbuf + rt * 2048 + lane * 4;
#pragma unroll
            for (int q = 0; q < 4; ++q)
                *(f32x4*)(xb + q * 256) =
                    (f32x4){acc0[q*4], acc0[q*4+1], acc0[q*4+2], acc0[q*4+3]};
#pragma unroll
            for (int q = 0; q < 4; ++q)
                *(f32x4*)(xb + (4 + q) * 256) =
                    (f32x4){acc1[q*4], acc1[q*4+1], acc1[q*4+2], acc1[q*4+3]};
        }
        __syncthreads();                          // C
        if (ks == 0) {
            const float* xb = xbuf + rt * 2048 + lane * 4;
#pragma unroll
            for (int q = 0; q < 4; ++q) {
                f32x4 p = *(const f32x4*)(xb + q * 256);
                acc0[q*4] += p[0]; acc0[q*4+1] += p[1]; acc0[q*4+2] += p[2]; acc0[q*4+3] += p[3];
            }
#pragma unroll
            for (int q = 0; q < 4; ++q) {
                f32x4 p = *(const f32x4*)(xb + (4 + q) * 256);
                acc1[q*4] += p[0]; acc1[q*4+1] += p[1]; acc1[q*4+2] += p[2]; acc1[q*4+3] += p[3];
            }
            // epilogue: lane owns row r = rowbase+l31, j = qq*8+lh*4+jj;
            // i = acc0[ci], f = acc0[8+ci], g = acc1[ci], o = acc1[8+ci]
            unsigned short* sw = scr + rt * 512 + l31 * 16;
#pragma unroll
            for (int qq = 0; qq < 2; ++qq) {
                f32x4 ea4 = (f32x4){0.f, 0.f, 0.f, 0.f};
                if (t == 0)
                    ea4 = *(const f32x4*)(eimg + (size_t)(rowbase + l31) * 512
                                               + j0 + qq * 8 + lh * 4);
                bf16x4 hv;
#pragma unroll
                for (int jj = 0; jj < 4; ++jj) {
                    int ci = qq * 4 + jj;
                    float iv = sigm(acc0[ci]     + cbi[qq][jj]  + ea4[jj]);
                    float fv = sigm(acc0[8 + ci] + cbf_[qq][jj] + ea4[jj]);
                    float gv = tanh_fast(acc1[ci] + cbg[qq][jj] + ea4[jj]);
                    float ov = sigm(acc1[8 + ci] + cbo[qq][jj] + ea4[jj]);
                    float co = (t == 0) ? 0.f : cst[ci];
                    float cn = fv * co + iv * gv;
                    cst[ci] = cn;
                    hv[jj] = (short)f2bf(ov * tanh_fast(cn));
                }
                *(bf16x4*)(sw + qq * 8 + lh * 4) = hv;
            }
            asm volatile("s_waitcnt lgkmcnt(0)" ::: "memory");
            int4v v = *(const int4v*)(scr + rt * 512 + lane * 8);
            unsigned short* gp = hs + (size_t)t * (B_ * H_) + (size_t)jblk * 16384
                                    + (size_t)(rowbase + (lane >> 1)) * 16 + (lane & 1) * 8;
            asm volatile("global_store_dwordx4 %0, %1, off sc0 sc1" :: "v"(gp), "v"(v) : "memory");
        }
        if (t < T_ - 1) {
            // pre-compute x-part(t+1) while stores drain / flags propagate
            acc0 = ZERO16; acc1 = ZERO16;
            const unsigned short* xp = xbf + (size_t)(t + 1) * 131072
                                           + (size_t)(ks * 4) * 16384
                                           + (size_t)(rowbase + l31) * 16 + h8;
            bf16x8 xreg[4];
#pragma unroll
            for (int kk = 0; kk < 4; ++kk) xreg[kk] = *(const bf16x8*)(xp + kk * 16384);
            __builtin_amdgcn_sched_barrier(0);
            const unsigned short* wx = w_s + (size_t)l31 * 648 + ks * 64 + h8;
#pragma unroll
            for (int kk = 0; kk < 4; ++kk) {
                bf16x8 a0 = *(const bf16x8*)(wx + kk * 16);
                bf16x8 a1 = *(const bf16x8*)(wx + 32 * 648 + kk * 16);
                acc0 = MFMA32(a0, xreg[kk], acc0);
                acc1 = MFMA32(a1, xreg[kk], acc1);
            }
        }
    }
}

// ---------------- logits + log_softmax via MFMA ----------------
__global__ __launch_bounds__(256, 2) void logits_mfma(
        const unsigned short* __restrict__ hs,    // [T,32,1024,16] bf16 panel-major
        const unsigned short* __restrict__ wo,    // [128][512] bf16, k-major
        const float* __restrict__ ob,             // [128]
        float* __restrict__ out) {                // [65536,128]
    __shared__ unsigned short wos[128 * 264];
    const int tid = threadIdx.x;
    const int wave = tid >> 6, lane = tid & 63;
    const int quad = lane >> 4, l16 = lane & 15;
    const int row0 = blockIdx.x * 64 + wave * 16;
    const int trow = row0 >> 10;                  // all 16 rows of this wave share t
    const int b0 = row0 & 1023;
    const unsigned short* hbase = hs + (size_t)trow * (B_ * H_)
                                     + (size_t)(b0 + l16) * 16 + (quad & 1) * 8;
    f32x4 acc[8];
#pragma unroll
    for (int q = 0; q < 8; ++q) acc[q] = (f32x4){0.f, 0.f, 0.f, 0.f};

    for (int half = 0; half < 2; ++half) {
        __syncthreads();
        for (int e = tid; e < 128 * 32; e += 256) {
            int n = e >> 5, c8 = (e & 31) * 8;
            *(bf16x8*)(wos + n * 264 + c8) = *(const bf16x8*)(wo + n * 512 + half * 256 + c8);
        }
        __syncthreads();
#pragma unroll
        for (int ki = 0; ki < 8; ++ki) {
            int p = half * 16 + ki * 2 + (quad >> 1);
            bf16x8 a = *(const bf16x8*)(hbase + (size_t)p * 16384);
#pragma unroll
            for (int tn = 0; tn < 8; ++tn) {
                bf16x8 b = *(const bf16x8*)(wos + (tn * 16 + l16) * 264 + ki * 32 + quad * 8);
                acc[tn] = MFMA16(a, b, acc[tn]);
            }
        }
    }
    float bia[8];
#pragma unroll
    for (int tn = 0; tn < 8; ++tn) bia[tn] = ob[tn * 16 + l16];
#pragma unroll
    for (int reg = 0; reg < 4; ++reg) {
        float v[8];
        float m = -3.4e38f;
#pragma unroll
        for (int tn = 0; tn < 8; ++tn) { v[tn] = acc[tn][reg] + bia[tn]; m = fmaxf(m, v[tn]); }
#pragma unroll
        for (int off = 1; off < 16; off <<= 1) m = fmaxf(m, __shfl_xor(m, off, 64));
        float s = 0.f;
#pragma unroll
        for (int tn = 0; tn < 8; ++tn) s += __expf(v[tn] - m);
#pragma unroll
        for (int off = 1; off < 16; off <<= 1) s += __shfl_xor(s, off, 64);
        float z = m + __logf(s);
        int row = row0 + quad * 4 + reg;
        float* op = out + (size_t)row * 128;
#pragma unroll
        for (int tn = 0; tn < 8; ++tn) op[tn * 16 + l16] = v[tn] - z;
    }
}

extern "C" void kernel_launch(void* const* d_in, const int* in_sizes, int n_in,
                              void* d_out, int out_size, void* d_ws, size_t ws_size,
                              hipStream_t stream) {
    const float* inp     = (const float*)d_in[0];
    const float* img     = (const float*)d_in[1];
    const float* conv1_w = (const float*)d_in[2];
    const float* conv1_b = (const float*)d_in[3];
    const float* conv2_w = (const float*)d_in[4];
    const float* conv2_b = (const float*)d_in[5];
    const float* imgfc_w = (const float*)d_in[6];
    const float* imgfc_b = (const float*)d_in[7];
    const float* xh_w    = (const float*)d_in[8];
    const float* xh_b    = (const float*)d_in[9];
    const float* hh_w    = (const float*)d_in[10];
    const float* hh_b    = (const float*)d_in[11];
    const float* out_w   = (const float*)d_in[12];
    const float* out_b   = (const float*)d_in[13];

    // ws layout (~90 MB). conv1out/feat alias the hs region (dead before
    // lstm_persist writes hs[0]).
    char* ws = (char*)d_ws;
    unsigned short* hs  = (unsigned short*)(ws);                   // [0,64M): panel-major bf16
    float* conv1out     = (float*)(ws);                            // [0,32M) alias
    float* feat         = (float*)(ws + (32u << 20));              // [32,46.2M) alias
    float* e            = (float*)(ws + (64u << 20));              // 2 MB
    float* cbias        = (float*)(ws + (66u << 20));              // 8 KB
    unsigned short* xbf = (unsigned short*)(ws + (67u << 20));     // 16 MB panel-major
    unsigned short* wt  = (unsigned short*)(ws + (83u << 20));     // 2.56 MB
    unsigned short* wo  = (unsigned short*)(ws + (86u << 20));     // 128 KB
    unsigned int*  ctr  = (unsigned int*)(ws + (87u << 20));       // flags [8][64]
    float* outp         = (float*)d_out;

    cbias_k<<<8, 256, 0, stream>>>(xh_b, hh_b, cbias, ctr);
    convx_k<<<(T_ * B_ * 8) / 256, 256, 0, stream>>>(inp, xbf);
    convw_k<<<(2048 * 640) / 256, 256, 0, stream>>>(xh_w, hh_w, wt);
    convow_k<<<(128 * 512) / 256, 256, 0, stream>>>(out_w, wo);
    conv1_k<<<(B_ * 8 * 32 * 32) / 256, 256, 0, stream>>>(img, conv1_w, conv1_b, conv1out);
    conv2_k<<<B_, 256, 0, stream>>>(conv1out, conv2_w, conv2_b, feat);
    imgfc_gemm<<<dim3(16, 16), 256, 0, stream>>>(feat, imgfc_w, imgfc_b, e);

    lstm_persist<<<256, 512, 82944 + 32768 + 4096, stream>>>(
        xbf, wt, cbias, e, hs, ctr);

    logits_mfma<<<(T_ * B_) / 64, 256, 0, stream>>>(hs, wo, out_b, outp);
}